// Round 2
// baseline (1630.752 us; speedup 1.0000x reference)
//
#include <hip/hip_runtime.h>
#include <stdint.h>

// ---------------- types ----------------
typedef _Float16 half_t;
typedef _Float16 half8 __attribute__((ext_vector_type(8)));
typedef _Float16 half4 __attribute__((ext_vector_type(4)));
typedef float f32x16 __attribute__((ext_vector_type(16)));
typedef float f32x4  __attribute__((ext_vector_type(4)));

// ---------------- problem constants ----------------
#define OBS_D 128
#define ACT_D 32
#define IN_D  160            // OBS_D + ACT_D
#define H_D   512
#define T_H   63             // horizon
#define NROWS 2048           // B*N = 32*64
#define KTOT  672            // IN_D + H_D
#define KT_ALL 42            // KTOT/16
#define KT_X   10            // IN_D/16
#define NT_ALL 48            // 1536/32
#define RB     32            // rows per block in recurrent kernel
#define NBLK   64            // NROWS/RB
#define PRED_ELEMS (NROWS*T_H*OBS_D)   // 16515072 ; hs starts here in d_out

#define ZERO16 {0.f,0.f,0.f,0.f,0.f,0.f,0.f,0.f,0.f,0.f,0.f,0.f,0.f,0.f,0.f,0.f}
#define MFMA16 __builtin_amdgcn_mfma_f32_32x32x16_f16

__device__ __forceinline__ float sigm(float x) {
    return __builtin_amdgcn_rcpf(1.0f + __expf(-x));
}
__device__ __forceinline__ float tanh_f(float x) {
    // robust for large |x|: expf->inf -> rcp->0 -> -1 ; expf->0 -> 2-1 = +1
    return 2.0f * __builtin_amdgcn_rcpf(1.0f + __expf(-2.0f * x)) - 1.0f;
}

// ============================================================================
// pack_w: W = [w_ih | w_hh] (gates x 672) and w_dec (128 x 512) -> fp16
// B-fragment order for mfma_32x32x16: frag[nt][kt][lane][j] = W[n][k],
//   n = nt*32 + (lane&31), k = kt*16 + (lane>>5)*8 + j
// ============================================================================
__global__ void pack_w(const float* __restrict__ w_ih, const float* __restrict__ w_hh,
                       const float* __restrict__ w_dec,
                       half_t* __restrict__ wpack, half_t* __restrict__ wdpack) {
    int idx = blockIdx.x * 256 + threadIdx.x;
    int lane = idx & 63;
    int m = lane & 31;
    int khalf = lane >> 5;
    if (idx < NT_ALL * KT_ALL * 64) {
        int kt = (idx >> 6) % KT_ALL;
        int nt = idx / (64 * KT_ALL);
        int n = nt * 32 + m;
        int k0 = kt * 16 + khalf * 8;
        half8 o;
        #pragma unroll
        for (int j = 0; j < 8; ++j) {
            int k = k0 + j;
            float v = (k < IN_D) ? w_ih[(size_t)n * IN_D + k]
                                 : w_hh[(size_t)n * H_D + (k - IN_D)];
            o[j] = (half_t)v;
        }
        *(half8*)(wpack + (size_t)idx * 8) = o;
    } else {
        int r = idx - NT_ALL * KT_ALL * 64;   // < 8192
        int kt = (r >> 6) % 32;
        int nt = r / (64 * 32);
        int n = nt * 32 + m;                  // output col (0..127)
        int k0 = kt * 16 + khalf * 8;
        half8 o;
        #pragma unroll
        for (int j = 0; j < 8; ++j) o[j] = (half_t)w_dec[(size_t)n * H_D + k0 + j];
        *(half8*)(wdpack + (size_t)r * 8) = o;
    }
}

// ============================================================================
// pack_x v2 (coalesced): one block per (rb, t). Stage 32x160 fp16 rows in LDS
// from fully-coalesced f32x4 loads, then emit 640 half8 A-fragments.
// ============================================================================
__global__ __launch_bounds__(256) void pack_x(const float* __restrict__ obs,
                                              const float* __restrict__ act,
                                              half_t* __restrict__ xfrag) {
    __shared__ __align__(16) half_t xs[32 * 160];   // 10240 B
    const int tid = threadIdx.x;
    const int bid = blockIdx.x;
    const int rb = bid / T_H;
    const int t  = bid % T_H;
    const int b  = rb >> 1;
    const int nbase = (rb & 1) * 32;

    // obs rows are contiguous: 32 rows x 128 floats
    const f32x4* ob = (const f32x4*)(obs + ((size_t)(b * 64 + t) * 64 + nbase) * OBS_D);
    #pragma unroll
    for (int i = tid; i < 1024; i += 256) {
        f32x4 v = ob[i];
        int flat = i * 4;
        int m = flat >> 7, k = flat & 127;
        half4 o; o[0]=(half_t)v[0]; o[1]=(half_t)v[1]; o[2]=(half_t)v[2]; o[3]=(half_t)v[3];
        *(half4*)(xs + m * 160 + k) = o;
    }
    // act rows: 32 rows x 32 floats (contiguous 1024 floats)
    {
        const f32x4* ac = (const f32x4*)(act + ((size_t)(b * 64 + t) * 64 + nbase) * ACT_D);
        f32x4 v = ac[tid];
        int flat = tid * 4;
        int m = flat >> 5, k = 128 + (flat & 31);
        half4 o; o[0]=(half_t)v[0]; o[1]=(half_t)v[1]; o[2]=(half_t)v[2]; o[3]=(half_t)v[3];
        *(half4*)(xs + m * 160 + k) = o;
    }
    __syncthreads();

    half_t* dst = xfrag + ((size_t)rb * T_H + t) * (KT_X * 512);
    for (int f = tid; f < KT_X * 64; f += 256) {
        int lane = f & 63, kt = f >> 6;
        int m = lane & 31;
        int k0 = kt * 16 + (lane >> 5) * 8;
        half8 o = *(const half8*)(xs + m * 160 + k0);
        *(half8*)(dst + (size_t)f * 8) = o;
    }
}

// ============================================================================
// gru_main v2: 64 blocks x 1024 threads (16 waves, 4/SIMD).
// Block rb owns rows rb*32..+32. Wave w owns h-dims [32w, 32w+32):
//   gate n-tiles: r = w, z = 16+w, n = 32+w (gi/gh K-split for the n gate).
// Per wave per step: 126 MFMA, 4 f32x16 accumulators (64 acc regs).
// ============================================================================
__global__ __launch_bounds__(1024) void gru_main(
        const half_t* __restrict__ wpack, const half_t* __restrict__ xfrag,
        const float* __restrict__ b_ih, const float* __restrict__ b_hh,
        float* __restrict__ out) {
    __shared__ __align__(16) half_t Abuf[KT_ALL * 64 * 8];   // 43008 B

    const int tid = threadIdx.x;
    const int w = tid >> 6;          // 0..15
    const int lane = tid & 63;
    const int col = lane & 31;
    const int khalf = lane >> 5;
    const int mbase = khalf * 4;
    const int rb = blockIdx.x;

    // ---- init: zero h-part of Abuf, copy x(t=0) into x-part ----
    {
        uint4* hz = (uint4*)(Abuf + KT_X * 512);
        for (int i = tid; i < (KT_ALL - KT_X) * 64; i += 1024)
            hz[i] = uint4{0, 0, 0, 0};
        const uint4* src = (const uint4*)(xfrag + (size_t)rb * T_H * (KT_X * 512));
        uint4* dstv = (uint4*)Abuf;
        for (int s = tid; s < KT_X * 64; s += 1024) dstv[s] = src[s];
    }

    // ---- per-lane constants ----
    const int d = w * 32 + col;              // this lane's h-dim
    const float br = b_ih[d] + b_hh[d];
    const float bz = b_ih[512 + d] + b_hh[512 + d];
    const float bi = b_ih[1024 + d];
    const float bh = b_hh[1024 + d];

    // B-fragment stream bases (element offsets; +512 per kt)
    const half_t* wr = wpack + ((size_t)w         * KT_ALL) * 512 + lane * 8;
    const half_t* wz = wpack + ((size_t)(16 + w)  * KT_ALL) * 512 + lane * 8;
    const half_t* wn = wpack + ((size_t)(32 + w)  * KT_ALL) * 512 + lane * 8;

    const int b_out = rb >> 1;
    const int nn_base = (rb & 1) << 5;

    // h master (fp32) in C/D layout registers
    float h[16];
    #pragma unroll
    for (int i = 0; i < 16; ++i) h[i] = 0.0f;

    // scatter-write constants (C/D reg -> A-frag LDS position)
    const int lp = 32 * ((col >> 3) & 1);
    const int jj = col & 7;
    const int ktb = KT_X + 2 * w + (col >> 4);

    __syncthreads();

    for (int t = 0; t < T_H; ++t) {
        f32x16 ar = ZERO16, az = ZERO16, ai = ZERO16, ah = ZERO16;
        const half8* Af = (const half8*)Abuf + lane;

        #pragma unroll 2
        for (int kt = 0; kt < KT_X; ++kt) {           // x part: r, z, gi_n
            half8 a = Af[kt * 64];
            ar = MFMA16(a, *(const half8*)(wr + kt * 512), ar, 0, 0, 0);
            az = MFMA16(a, *(const half8*)(wz + kt * 512), az, 0, 0, 0);
            ai = MFMA16(a, *(const half8*)(wn + kt * 512), ai, 0, 0, 0);
        }
        #pragma unroll 2
        for (int kt = KT_X; kt < KT_ALL; ++kt) {      // h part: r, z, gh_n
            half8 a = Af[kt * 64];
            ar = MFMA16(a, *(const half8*)(wr + kt * 512), ar, 0, 0, 0);
            az = MFMA16(a, *(const half8*)(wz + kt * 512), az, 0, 0, 0);
            ah = MFMA16(a, *(const half8*)(wn + kt * 512), ah, 0, 0, 0);
        }

        // ---- epilogue: gates -> h update -> global hs store ----
        float* hsrow = out + (size_t)PRED_ELEMS + ((size_t)(b_out * T_H + t)) * (64 * 512);
        #pragma unroll
        for (int r = 0; r < 16; ++r) {
            int m = (r & 3) + 8 * (r >> 2) + mbase;   // C/D row (verified mapping)
            float rr = sigm(ar[r] + br);
            float zz = sigm(az[r] + bz);
            float nn = tanh_f(ai[r] + bi + rr * (ah[r] + bh));
            float hv = (1.0f - zz) * nn + zz * h[r];
            h[r] = hv;
            hsrow[(size_t)(nn_base + m) * 512 + d] = hv;
        }

        __syncthreads();   // everyone done reading Abuf for step t

        if (t < T_H - 1) {
            // scatter h (fp16) into A-frag layout (kt >= KT_X region)
            #pragma unroll
            for (int r = 0; r < 16; ++r) {
                int m = (r & 3) + 8 * (r >> 2) + mbase;
                Abuf[ktb * 512 + (m + lp) * 8 + jj] = (half_t)h[r];
            }
            // copy x(t+1) into x-part
            const uint4* src = (const uint4*)(xfrag +
                ((size_t)rb * T_H + (t + 1)) * (size_t)(KT_X * 512));
            uint4* dstv = (uint4*)Abuf;
            for (int s = tid; s < KT_X * 64; s += 1024) dstv[s] = src[s];
        }
        __syncthreads();   // writes visible before next GEMM
    }
}

// ============================================================================
// dec_k v2: preds = hs @ w_dec^T + b_dec. 4032 blocks x 256 threads (4 waves).
// Block: 32 rows; wave w: output cols [w*32, w*32+32). No LDS: A-fragments
// gathered per-lane straight from the fp32 hs rows (L1/L2-resident; each
// row's 2 KB line is reused across the 32-kt sweep).
// ============================================================================
__global__ __launch_bounds__(256) void dec_k(
        const float* __restrict__ hs, const half_t* __restrict__ wdpack,
        const float* __restrict__ b_dec, float* __restrict__ preds) {
    const int tid = threadIdx.x, w = tid >> 6, lane = tid & 63;
    const size_t row0 = (size_t)blockIdx.x * 32;
    const int mA = lane & 31, k0 = (lane >> 5) * 8;

    const float* ap = hs + (row0 + mA) * 512 + k0;
    const half_t* wd = wdpack + ((size_t)w * 32) * 512 + lane * 8;

    f32x16 acc = ZERO16;
    #pragma unroll 4
    for (int kt = 0; kt < 32; ++kt) {
        f32x4 v0 = *(const f32x4*)(ap + kt * 16);
        f32x4 v1 = *(const f32x4*)(ap + kt * 16 + 4);
        half8 a;
        a[0]=(half_t)v0[0]; a[1]=(half_t)v0[1]; a[2]=(half_t)v0[2]; a[3]=(half_t)v0[3];
        a[4]=(half_t)v1[0]; a[5]=(half_t)v1[1]; a[6]=(half_t)v1[2]; a[7]=(half_t)v1[3];
        half8 b = *(const half8*)(wd + kt * 512);
        acc = MFMA16(a, b, acc, 0, 0, 0);
    }
    const int colD = w * 32 + (lane & 31);
    const float bd = b_dec[colD];
    #pragma unroll
    for (int r = 0; r < 16; ++r) {
        int m = (r & 3) + 8 * (r >> 2) + 4 * (lane >> 5);
        preds[(row0 + m) * 128 + colD] = acc[r] + bd;
    }
}

// ============================================================================
extern "C" void kernel_launch(void* const* d_in, const int* in_sizes, int n_in,
                              void* d_out, int out_size, void* d_ws, size_t ws_size,
                              hipStream_t stream) {
    const float* obs   = (const float*)d_in[0];
    const float* act   = (const float*)d_in[1];
    const float* w_ih  = (const float*)d_in[2];
    const float* w_hh  = (const float*)d_in[3];
    const float* b_ih  = (const float*)d_in[4];
    const float* b_hh  = (const float*)d_in[5];
    const float* w_dec = (const float*)d_in[6];
    const float* b_dec = (const float*)d_in[7];
    // d_in[8] = horizon (fixed 63; compiled in)
    float* out = (float*)d_out;

    // workspace layout (fp16 elements): wpack | wdpack | xfrag  ~= 41.5 MB
    half_t* wpack  = (half_t*)d_ws;                          // 48*42*512  = 1032192
    half_t* wdpack = wpack + (size_t)NT_ALL * KT_ALL * 512;  // 4*32*512   = 65536
    half_t* xfrag  = wdpack + (size_t)4 * 32 * 512;          // 64*63*5120 = 20643840

    hipLaunchKernelGGL(pack_w, dim3(536), dim3(256), 0, stream,
                       w_ih, w_hh, w_dec, wpack, wdpack);
    hipLaunchKernelGGL(pack_x, dim3(NBLK * T_H), dim3(256), 0, stream, obs, act, xfrag);
    hipLaunchKernelGGL(gru_main, dim3(NBLK), dim3(1024), 0, stream,
                       wpack, xfrag, b_ih, b_hh, out);
    hipLaunchKernelGGL(dec_k, dim3(NROWS * T_H / 32), dim3(256), 0, stream,
                       out + (size_t)PRED_ELEMS, wdpack, b_dec, out);
}